// Round 9
// baseline (134.798 us; speedup 1.0000x reference)
//
#include <hip/hip_runtime.h>

#define N_NODES 50000
#define N_EDGES 800000
#define NB_SCAN 196   // ceil(N_NODES/256)

typedef _Float16 f16x8 __attribute__((ext_vector_type(8)));
typedef _Float16 f16x4 __attribute__((ext_vector_type(4)));
typedef float    f32x4 __attribute__((ext_vector_type(4)));

__device__ __forceinline__ unsigned f16bits(float f) {
    const _Float16 h = (_Float16)f;
    return (unsigned)*(const unsigned short*)&h;
}
__device__ __forceinline__ float f16val(unsigned u) {
    const unsigned short us = (unsigned short)u;
    return (float)*(const _Float16*)&us;
}

// ---------------- K0: x -> fp16 copy (for the aggregate gather)
__global__ void xh_kernel(const float* __restrict__ x, _Float16* __restrict__ xh) {
    const int i = blockIdx.x * 256 + threadIdx.x;   // one float4 per thread
    if (i >= N_NODES * 16) return;
    const float4 v = *(const float4*)&x[(size_t)i * 4];
    f16x4 h;
    h[0] = (_Float16)v.x; h[1] = (_Float16)v.y;
    h[2] = (_Float16)v.z; h[3] = (_Float16)v.w;
    *(f16x4*)&xh[(size_t)i * 4] = h;
}

// ---------------- K1: histogram of destination degrees + rank assignment
__global__ void hist_kernel(const int* __restrict__ ei, int* __restrict__ counts,
                            int* __restrict__ rank) {
    int e = blockIdx.x * 256 + threadIdx.x;
    if (e < N_EDGES) rank[e] = atomicAdd(&counts[ei[N_EDGES + e]], 1);
}

// ---------------- K2a: per-block sums of counts
__global__ void scanA_kernel(const int* __restrict__ counts, int* __restrict__ bsum) {
    __shared__ int s[256];
    int i = blockIdx.x * 256 + threadIdx.x;
    s[threadIdx.x] = (i < N_NODES) ? counts[i] : 0;
    __syncthreads();
    for (int d = 128; d > 0; d >>= 1) {
        if (threadIdx.x < d) s[threadIdx.x] += s[threadIdx.x + d];
        __syncthreads();
    }
    if (threadIdx.x == 0) bsum[blockIdx.x] = s[0];
}

// ---------------- K2b: exclusive scan of block sums (1 block)
__global__ void scanB_kernel(const int* __restrict__ bsum, int* __restrict__ boff) {
    __shared__ int s[256];
    int tid = threadIdx.x;
    s[tid] = (tid < NB_SCAN) ? bsum[tid] : 0;
    __syncthreads();
    for (int d = 1; d < 256; d <<= 1) {
        int v = (tid >= d) ? s[tid - d] : 0;
        __syncthreads();
        s[tid] += v;
        __syncthreads();
    }
    if (tid < NB_SCAN) boff[tid] = (tid == 0) ? 0 : s[tid - 1];
}

// ---------------- K2c: per-element exclusive offsets
__global__ void scanC_kernel(const int* __restrict__ counts, const int* __restrict__ boff,
                             int* __restrict__ off) {
    __shared__ int s[256];
    int tid = threadIdx.x;
    int i = blockIdx.x * 256 + tid;
    int v = (i < N_NODES) ? counts[i] : 0;
    s[tid] = v;
    __syncthreads();
    for (int d = 1; d < 256; d <<= 1) {
        int t = (tid >= d) ? s[tid - d] : 0;
        __syncthreads();
        s[tid] += t;
        __syncthreads();
    }
    int excl = s[tid] - v + boff[blockIdx.x];
    if (i < N_NODES) off[i] = excl;
    if (i == 0) off[N_NODES] = N_EDGES;
}

// ---------------- K3: compute f16 gaussian weights, scatter 8B {src:u16,w0,w1,w2}
__global__ void scatter_kernel(const int* __restrict__ ei,
                               const float* __restrict__ pseudo,
                               const float* __restrict__ mu,
                               const float* __restrict__ sigma,
                               const int* __restrict__ off,
                               const int* __restrict__ rank,
                               int2* __restrict__ packed) {
    int e = blockIdx.x * 256 + threadIdx.x;
    if (e >= N_EDGES) return;
    const float mu0 = mu[0], mu1 = mu[1], mu2 = mu[2];
    const float s0 = sigma[0], s1 = sigma[1], s2 = sigma[2];
    const float c0 = -0.5f / (1e-14f + s0 * s0);
    const float c1 = -0.5f / (1e-14f + s1 * s1);
    const float c2 = -0.5f / (1e-14f + s2 * s2);
    const int s  = ei[e];
    const int dd = ei[N_EDGES + e];
    const float u = pseudo[e];
    const float d0 = u - mu0, d1 = u - mu1, d2 = u - mu2;
    const unsigned w0 = f16bits(__expf(c0 * d0 * d0));
    const unsigned w1 = f16bits(__expf(c1 * d1 * d1));
    const unsigned w2 = f16bits(__expf(c2 * d2 * d2));
    const int pos = off[dd] + rank[e];
    packed[pos] = make_int2((int)((unsigned)s | (w0 << 16)), (int)(w1 | (w2 << 16)));
}

// ---------------- K4: wave-per-node gather of fp16 x rows -> fp16 agg[n][0:256]
__global__ void aggregate_kernel(const _Float16* __restrict__ xh,
                                 const int2* __restrict__ packed,
                                 const int* __restrict__ off,
                                 _Float16* __restrict__ aggmh) {
    const int lane = threadIdx.x & 63;
    const int node = blockIdx.x * 4 + (threadIdx.x >> 6);
    if (node >= N_NODES) return;
    const int start = off[node], end = off[node + 1];
    float a0 = 0.f, a1 = 0.f, a2 = 0.f;
    int j = start;
    for (; j + 1 < end; j += 2) {
        const int2 r0 = packed[j];
        const int2 r1 = packed[j + 1];
        const float xv0 = (float)xh[(size_t)(r0.x & 0xFFFF) * 64 + lane];
        const float xv1 = (float)xh[(size_t)(r1.x & 0xFFFF) * 64 + lane];
        a0 += f16val((unsigned)r0.x >> 16) * xv0 + f16val((unsigned)r1.x >> 16) * xv1;
        a1 += f16val(r0.y & 0xFFFF) * xv0 + f16val(r1.y & 0xFFFF) * xv1;
        a2 += f16val((unsigned)r0.y >> 16) * xv0 + f16val((unsigned)r1.y >> 16) * xv1;
    }
    if (j < end) {
        const int2 r = packed[j];
        const float xv = (float)xh[(size_t)(r.x & 0xFFFF) * 64 + lane];
        a0 += f16val((unsigned)r.x >> 16) * xv;
        a1 += f16val(r.y & 0xFFFF) * xv;
        a2 += f16val((unsigned)r.y >> 16) * xv;
    }
    const float inv = 1.0f / fmaxf((float)(end - start), 1.0f);
    _Float16* row = aggmh + (size_t)node * 256;
    row[lane]       = (_Float16)(a0 * inv);
    row[64 + lane]  = (_Float16)(a1 * inv);
    row[128 + lane] = (_Float16)(a2 * inv);
    row[192 + lane] = xh[(size_t)node * 64 + lane];   // for the fused x@root
}

// ---------------- K5a: pre-pack W into MFMA B-fragment layout (fp16)
// W[k][d]: k<192 -> g[k&63][(k>>6)*64+d]; k>=192 -> root[k-192][d]
__global__ void wprep_kernel(const float* __restrict__ g,
                             const float* __restrict__ root,
                             _Float16* __restrict__ wfrag) {
    const int t = blockIdx.x * 256 + threadIdx.x;
    if (t >= 2048) return;
    const int lane = t & 63;
    const int cc   = (t >> 6) & 3;
    const int kc   = t >> 8;
    const int d     = cc * 16 + (lane & 15);
    const int kbase = kc * 32 + (lane >> 4) * 8;
    f16x8 v;
#pragma unroll
    for (int i = 0; i < 8; ++i) {
        const int k = kbase + i;
        const float w = (k < 192) ? g[(k & 63) * 192 + (k >> 6) * 64 + d]
                                  : root[(k - 192) * 64 + d];
        v[i] = (_Float16)w;
    }
    *(f16x8*)&wfrag[(size_t)t * 8] = v;
}

// ---------------- K5b: MFMA GEMM [50000,256]x[256,64] + bias + fp32 residual + silu
#define BF(kc, c) (*(const f16x8*)&sWf[((((kc) * 4 + (c)) * 64 + lane) * 8)])
#define MFMA16(a, b, c) __builtin_amdgcn_mfma_f32_16x16x32_f16(a, b, c, 0, 0, 0)
#define COLTILE(c, accv)                                   \
    accv = MFMA16(af0, BF(0, c), accv);                    \
    accv = MFMA16(af1, BF(1, c), accv);                    \
    accv = MFMA16(af2, BF(2, c), accv);                    \
    accv = MFMA16(af3, BF(3, c), accv);                    \
    accv = MFMA16(af4, BF(4, c), accv);                    \
    accv = MFMA16(af5, BF(5, c), accv);                    \
    accv = MFMA16(af6, BF(6, c), accv);                    \
    accv = MFMA16(af7, BF(7, c), accv);
#define EPILOG(c, accv)                                                        \
    {                                                                          \
        const int col = (c) * 16 + (lane & 15);                                \
        const float bv = bias[col];                                            \
        _Pragma("unroll")                                                      \
        for (int r = 0; r < 4; ++r) {                                          \
            const int rr = orow + r;                                           \
            const float v = accv[r] + bv + x[(size_t)rr * 64 + col];           \
            out[(size_t)rr * 64 + col] = v / (1.0f + expf(-v));                \
        }                                                                      \
    }

__global__ __launch_bounds__(256)
void mfma_gemm_kernel(const _Float16* __restrict__ aggmh,
                      const _Float16* __restrict__ wfrag,
                      const float* __restrict__ x,
                      const float* __restrict__ bias,
                      float* __restrict__ out) {
    __shared__ _Float16 sWf[2048 * 8];   // 32 KB: full W in fragment layout
    const int tid = threadIdx.x;
    for (int i = tid; i < 2048; i += 256)
        *(f16x8*)&sWf[i * 8] = *(const f16x8*)&wfrag[(size_t)i * 8];
    __syncthreads();

    const int lane = tid & 63;
    const int wid  = tid >> 6;
    const int row0 = blockIdx.x * 64 + wid * 16;
    if (row0 >= N_NODES) return;

    const size_t abase = (size_t)(row0 + (lane & 15)) * 256 + (lane >> 4) * 8;
    const f16x8 af0 = *(const f16x8*)&aggmh[abase + 0 * 32];
    const f16x8 af1 = *(const f16x8*)&aggmh[abase + 1 * 32];
    const f16x8 af2 = *(const f16x8*)&aggmh[abase + 2 * 32];
    const f16x8 af3 = *(const f16x8*)&aggmh[abase + 3 * 32];
    const f16x8 af4 = *(const f16x8*)&aggmh[abase + 4 * 32];
    const f16x8 af5 = *(const f16x8*)&aggmh[abase + 5 * 32];
    const f16x8 af6 = *(const f16x8*)&aggmh[abase + 6 * 32];
    const f16x8 af7 = *(const f16x8*)&aggmh[abase + 7 * 32];

    f32x4 acc0 = {0.f, 0.f, 0.f, 0.f};
    f32x4 acc1 = {0.f, 0.f, 0.f, 0.f};
    f32x4 acc2 = {0.f, 0.f, 0.f, 0.f};
    f32x4 acc3 = {0.f, 0.f, 0.f, 0.f};
    COLTILE(0, acc0)
    COLTILE(1, acc1)
    COLTILE(2, acc2)
    COLTILE(3, acc3)

    const int orow = row0 + (lane >> 4) * 4;   // D: col=lane&15, row=(lane>>4)*4+reg
    EPILOG(0, acc0)
    EPILOG(1, acc1)
    EPILOG(2, acc2)
    EPILOG(3, acc3)
}

extern "C" void kernel_launch(void* const* d_in, const int* in_sizes, int n_in,
                              void* d_out, int out_size, void* d_ws, size_t ws_size,
                              hipStream_t stream) {
    const float* x     = (const float*)d_in[0];
    const int*   ei    = (const int*)d_in[1];
    const float* ea    = (const float*)d_in[2];
    const float* g     = (const float*)d_in[3];
    const float* mu    = (const float*)d_in[4];
    const float* sigma = (const float*)d_in[5];
    const float* root  = (const float*)d_in[6];
    const float* bias  = (const float*)d_in[7];
    float* out = (float*)d_out;

    char* ws = (char*)d_ws;
    const size_t aggmh_bytes  = (size_t)N_NODES * 256 * sizeof(_Float16); // 25.6 MB
    const size_t xh_bytes     = (size_t)N_NODES * 64 * sizeof(_Float16);  //  6.4 MB
    const size_t packed_bytes = (size_t)N_EDGES * sizeof(int2);           //  6.4 MB
    const size_t rank_bytes   = (size_t)N_EDGES * sizeof(int);            //  3.2 MB
    const size_t wfrag_bytes  = (size_t)2048 * 8 * sizeof(_Float16);      //  32 KB
    _Float16* aggmh  = (_Float16*)ws;
    _Float16* xh     = (_Float16*)(ws + aggmh_bytes);
    int2*     packed = (int2*)(ws + aggmh_bytes + xh_bytes);
    int*      rank   = (int*)(ws + aggmh_bytes + xh_bytes + packed_bytes);
    _Float16* wfrag  = (_Float16*)(ws + aggmh_bytes + xh_bytes + packed_bytes + rank_bytes);
    int* counts = (int*)(ws + aggmh_bytes + xh_bytes + packed_bytes + rank_bytes + wfrag_bytes);
    int* off    = counts + N_NODES;           // N_NODES+1 entries
    int* bsum   = off + N_NODES + 1;
    int* boff   = bsum + NB_SCAN;

    hipMemsetAsync(counts, 0, N_NODES * sizeof(int), stream);

    xh_kernel<<<(N_NODES * 16 + 255) / 256, 256, 0, stream>>>(x, xh);
    hist_kernel<<<(N_EDGES + 255) / 256, 256, 0, stream>>>(ei, counts, rank);
    scanA_kernel<<<NB_SCAN, 256, 0, stream>>>(counts, bsum);
    scanB_kernel<<<1, 256, 0, stream>>>(bsum, boff);
    scanC_kernel<<<NB_SCAN, 256, 0, stream>>>(counts, boff, off);
    scatter_kernel<<<(N_EDGES + 255) / 256, 256, 0, stream>>>(ei, ea, mu, sigma, off, rank, packed);
    wprep_kernel<<<8, 256, 0, stream>>>(g, root, wfrag);
    aggregate_kernel<<<(N_NODES + 3) / 4, 256, 0, stream>>>(xh, packed, off, aggmh);
    mfma_gemm_kernel<<<(N_NODES + 63) / 64, 256, 0, stream>>>(aggmh, wfrag, x, bias, out);
}

// Round 10
// 111.879 us; speedup vs baseline: 1.2049x; 1.2049x over previous
//
#include <hip/hip_runtime.h>

#define N_NODES 50000
#define N_EDGES 800000
#define NB_SCAN 196   // ceil(N_NODES/256)

typedef _Float16 f16x8 __attribute__((ext_vector_type(8)));
typedef _Float16 f16x4 __attribute__((ext_vector_type(4)));
typedef float    f32x4 __attribute__((ext_vector_type(4)));

__device__ __forceinline__ unsigned f16bits(float f) {
    const _Float16 h = (_Float16)f;
    return (unsigned)*(const unsigned short*)&h;
}
__device__ __forceinline__ float f16val(unsigned u) {
    const unsigned short us = (unsigned short)u;
    return (float)*(const _Float16*)&us;
}

// ---------------- K0: x -> fp16 copy (for the aggregate gather)
__global__ void xh_kernel(const float* __restrict__ x, _Float16* __restrict__ xh) {
    const int i = blockIdx.x * 256 + threadIdx.x;   // one float4 per thread
    if (i >= N_NODES * 16) return;
    const float4 v = *(const float4*)&x[(size_t)i * 4];
    f16x4 h;
    h[0] = (_Float16)v.x; h[1] = (_Float16)v.y;
    h[2] = (_Float16)v.z; h[3] = (_Float16)v.w;
    *(f16x4*)&xh[(size_t)i * 4] = h;
}

// ---------------- K1: histogram of destination degrees + rank assignment
__global__ void hist_kernel(const int* __restrict__ ei, int* __restrict__ counts,
                            int* __restrict__ rank) {
    int e = blockIdx.x * 256 + threadIdx.x;
    if (e < N_EDGES) rank[e] = atomicAdd(&counts[ei[N_EDGES + e]], 1);
}

// ---------------- K2a: per-block sums of counts
__global__ void scanA_kernel(const int* __restrict__ counts, int* __restrict__ bsum) {
    __shared__ int s[256];
    int i = blockIdx.x * 256 + threadIdx.x;
    s[threadIdx.x] = (i < N_NODES) ? counts[i] : 0;
    __syncthreads();
    for (int d = 128; d > 0; d >>= 1) {
        if (threadIdx.x < d) s[threadIdx.x] += s[threadIdx.x + d];
        __syncthreads();
    }
    if (threadIdx.x == 0) bsum[blockIdx.x] = s[0];
}

// ---------------- K2c: per-element exclusive offsets (block prefix derived in-kernel)
__global__ void scanC_kernel(const int* __restrict__ counts, const int* __restrict__ bsum,
                             int* __restrict__ off) {
    __shared__ int s[256];
    __shared__ int rs[256];
    const int tid = threadIdx.x;
    // block offset = sum of bsum[0 .. blockIdx.x-1]
    rs[tid] = (tid < NB_SCAN && tid < blockIdx.x) ? bsum[tid] : 0;
    __syncthreads();
    for (int d = 128; d > 0; d >>= 1) {
        if (tid < d) rs[tid] += rs[tid + d];
        __syncthreads();
    }
    const int boff = rs[0];
    const int i = blockIdx.x * 256 + tid;
    const int v = (i < N_NODES) ? counts[i] : 0;
    s[tid] = v;
    __syncthreads();
    for (int d = 1; d < 256; d <<= 1) {
        int t = (tid >= d) ? s[tid - d] : 0;
        __syncthreads();
        s[tid] += t;
        __syncthreads();
    }
    const int excl = s[tid] - v + boff;
    if (i < N_NODES) off[i] = excl;
    if (i == 0) off[N_NODES] = N_EDGES;
}

// ---------------- K3: compute f16 gaussian weights, scatter 8B {src:u16,w0,w1,w2}
__global__ void scatter_kernel(const int* __restrict__ ei,
                               const float* __restrict__ pseudo,
                               const float* __restrict__ mu,
                               const float* __restrict__ sigma,
                               const int* __restrict__ off,
                               const int* __restrict__ rank,
                               int2* __restrict__ packed) {
    int e = blockIdx.x * 256 + threadIdx.x;
    if (e >= N_EDGES) return;
    const float mu0 = mu[0], mu1 = mu[1], mu2 = mu[2];
    const float s0 = sigma[0], s1 = sigma[1], s2 = sigma[2];
    const float c0 = -0.5f / (1e-14f + s0 * s0);
    const float c1 = -0.5f / (1e-14f + s1 * s1);
    const float c2 = -0.5f / (1e-14f + s2 * s2);
    const int s  = ei[e];
    const int dd = ei[N_EDGES + e];
    const float u = pseudo[e];
    const float d0 = u - mu0, d1 = u - mu1, d2 = u - mu2;
    const unsigned w0 = f16bits(__expf(c0 * d0 * d0));
    const unsigned w1 = f16bits(__expf(c1 * d1 * d1));
    const unsigned w2 = f16bits(__expf(c2 * d2 * d2));
    const int pos = off[dd] + rank[e];
    packed[pos] = make_int2((int)((unsigned)s | (w0 << 16)), (int)(w1 | (w2 << 16)));
}

// ---------------- K4: wave-per-node gather. Records loaded 64-wide coalesced,
// walked via __shfl broadcast; 4 independent xh-gathers in flight per step.
__global__ void aggregate_kernel(const _Float16* __restrict__ xh,
                                 const int2* __restrict__ packed,
                                 const int* __restrict__ off,
                                 _Float16* __restrict__ aggmh) {
    const int lane = threadIdx.x & 63;
    const int node = blockIdx.x * 4 + (threadIdx.x >> 6);
    if (node >= N_NODES) return;
    const int start = off[node], end = off[node + 1];
    float a0 = 0.f, a1 = 0.f, a2 = 0.f;
    for (int base = start; base < end; base += 64) {
        const int nrec = min(64, end - base);
        int2 rec = make_int2(0, 0);
        if (lane < nrec) rec = packed[base + lane];   // coalesced 64-record load
        int j = 0;
        for (; j + 4 <= nrec; j += 4) {
            const int rx0 = __shfl(rec.x, j + 0), ry0 = __shfl(rec.y, j + 0);
            const int rx1 = __shfl(rec.x, j + 1), ry1 = __shfl(rec.y, j + 1);
            const int rx2 = __shfl(rec.x, j + 2), ry2 = __shfl(rec.y, j + 2);
            const int rx3 = __shfl(rec.x, j + 3), ry3 = __shfl(rec.y, j + 3);
            const float xv0 = (float)xh[(size_t)(rx0 & 0xFFFF) * 64 + lane];
            const float xv1 = (float)xh[(size_t)(rx1 & 0xFFFF) * 64 + lane];
            const float xv2 = (float)xh[(size_t)(rx2 & 0xFFFF) * 64 + lane];
            const float xv3 = (float)xh[(size_t)(rx3 & 0xFFFF) * 64 + lane];
            a0 += f16val((unsigned)rx0 >> 16) * xv0 + f16val((unsigned)rx1 >> 16) * xv1
                + f16val((unsigned)rx2 >> 16) * xv2 + f16val((unsigned)rx3 >> 16) * xv3;
            a1 += f16val(ry0 & 0xFFFF) * xv0 + f16val(ry1 & 0xFFFF) * xv1
                + f16val(ry2 & 0xFFFF) * xv2 + f16val(ry3 & 0xFFFF) * xv3;
            a2 += f16val((unsigned)ry0 >> 16) * xv0 + f16val((unsigned)ry1 >> 16) * xv1
                + f16val((unsigned)ry2 >> 16) * xv2 + f16val((unsigned)ry3 >> 16) * xv3;
        }
        for (; j < nrec; ++j) {
            const int rx = __shfl(rec.x, j), ry = __shfl(rec.y, j);
            const float xv = (float)xh[(size_t)(rx & 0xFFFF) * 64 + lane];
            a0 += f16val((unsigned)rx >> 16) * xv;
            a1 += f16val(ry & 0xFFFF) * xv;
            a2 += f16val((unsigned)ry >> 16) * xv;
        }
    }
    const float inv = 1.0f / fmaxf((float)(end - start), 1.0f);
    _Float16* row = aggmh + (size_t)node * 256;
    row[lane]       = (_Float16)(a0 * inv);
    row[64 + lane]  = (_Float16)(a1 * inv);
    row[128 + lane] = (_Float16)(a2 * inv);
    row[192 + lane] = xh[(size_t)node * 64 + lane];   // for the fused x@root + residual
}

// ---------------- K5a: pre-pack W into MFMA B-fragment layout (fp16)
// W[k][d]: k<192 -> g[k&63][(k>>6)*64+d]; k>=192 -> root[k-192][d]
__global__ void wprep_kernel(const float* __restrict__ g,
                             const float* __restrict__ root,
                             _Float16* __restrict__ wfrag) {
    const int t = blockIdx.x * 256 + threadIdx.x;
    if (t >= 2048) return;
    const int lane = t & 63;
    const int cc   = (t >> 6) & 3;
    const int kc   = t >> 8;
    const int d     = cc * 16 + (lane & 15);
    const int kbase = kc * 32 + (lane >> 4) * 8;
    f16x8 v;
#pragma unroll
    for (int i = 0; i < 8; ++i) {
        const int k = kbase + i;
        const float w = (k < 192) ? g[(k & 63) * 192 + (k >> 6) * 64 + d]
                                  : root[(k - 192) * 64 + d];
        v[i] = (_Float16)w;
    }
    *(f16x8*)&wfrag[(size_t)t * 8] = v;
}

// ---------------- K5b: MFMA GEMM [50000,256]x[256,64] + bias + residual + silu
#define BF(kc, c) (*(const f16x8*)&sWf[((((kc) * 4 + (c)) * 64 + lane) * 8)])
#define MFMA16(a, b, c) __builtin_amdgcn_mfma_f32_16x16x32_f16(a, b, c, 0, 0, 0)
#define COLTILE(c, accv)                                   \
    accv = MFMA16(af0, BF(0, c), accv);                    \
    accv = MFMA16(af1, BF(1, c), accv);                    \
    accv = MFMA16(af2, BF(2, c), accv);                    \
    accv = MFMA16(af3, BF(3, c), accv);                    \
    accv = MFMA16(af4, BF(4, c), accv);                    \
    accv = MFMA16(af5, BF(5, c), accv);                    \
    accv = MFMA16(af6, BF(6, c), accv);                    \
    accv = MFMA16(af7, BF(7, c), accv);
#define EPILOG(c, accv)                                                          \
    {                                                                            \
        const int col = (c) * 16 + (lane & 15);                                  \
        const float bv = bias[col];                                              \
        _Pragma("unroll")                                                        \
        for (int r = 0; r < 4; ++r) {                                            \
            const int rr = orow + r;                                             \
            const float res = (float)aggmh[(size_t)rr * 256 + 192 + col];        \
            const float v = accv[r] + bv + res;                                  \
            out[(size_t)rr * 64 + col] = v / (1.0f + expf(-v));                  \
        }                                                                        \
    }

__global__ __launch_bounds__(256)
void mfma_gemm_kernel(const _Float16* __restrict__ aggmh,
                      const _Float16* __restrict__ wfrag,
                      const float* __restrict__ bias,
                      float* __restrict__ out) {
    __shared__ _Float16 sWf[2048 * 8];   // 32 KB: full W in fragment layout
    const int tid = threadIdx.x;
    for (int i = tid; i < 2048; i += 256)
        *(f16x8*)&sWf[i * 8] = *(const f16x8*)&wfrag[(size_t)i * 8];
    __syncthreads();

    const int lane = tid & 63;
    const int wid  = tid >> 6;
    const int row0 = blockIdx.x * 64 + wid * 16;
    if (row0 >= N_NODES) return;

    const size_t abase = (size_t)(row0 + (lane & 15)) * 256 + (lane >> 4) * 8;
    const f16x8 af0 = *(const f16x8*)&aggmh[abase + 0 * 32];
    const f16x8 af1 = *(const f16x8*)&aggmh[abase + 1 * 32];
    const f16x8 af2 = *(const f16x8*)&aggmh[abase + 2 * 32];
    const f16x8 af3 = *(const f16x8*)&aggmh[abase + 3 * 32];
    const f16x8 af4 = *(const f16x8*)&aggmh[abase + 4 * 32];
    const f16x8 af5 = *(const f16x8*)&aggmh[abase + 5 * 32];
    const f16x8 af6 = *(const f16x8*)&aggmh[abase + 6 * 32];
    const f16x8 af7 = *(const f16x8*)&aggmh[abase + 7 * 32];

    f32x4 acc0 = {0.f, 0.f, 0.f, 0.f};
    f32x4 acc1 = {0.f, 0.f, 0.f, 0.f};
    f32x4 acc2 = {0.f, 0.f, 0.f, 0.f};
    f32x4 acc3 = {0.f, 0.f, 0.f, 0.f};
    COLTILE(0, acc0)
    COLTILE(1, acc1)
    COLTILE(2, acc2)
    COLTILE(3, acc3)

    const int orow = row0 + (lane >> 4) * 4;   // D: col=lane&15, row=(lane>>4)*4+reg
    EPILOG(0, acc0)
    EPILOG(1, acc1)
    EPILOG(2, acc2)
    EPILOG(3, acc3)
}

extern "C" void kernel_launch(void* const* d_in, const int* in_sizes, int n_in,
                              void* d_out, int out_size, void* d_ws, size_t ws_size,
                              hipStream_t stream) {
    const float* x     = (const float*)d_in[0];
    const int*   ei    = (const int*)d_in[1];
    const float* ea    = (const float*)d_in[2];
    const float* g     = (const float*)d_in[3];
    const float* mu    = (const float*)d_in[4];
    const float* sigma = (const float*)d_in[5];
    const float* root  = (const float*)d_in[6];
    const float* bias  = (const float*)d_in[7];
    float* out = (float*)d_out;

    char* ws = (char*)d_ws;
    const size_t aggmh_bytes  = (size_t)N_NODES * 256 * sizeof(_Float16); // 25.6 MB
    const size_t xh_bytes     = (size_t)N_NODES * 64 * sizeof(_Float16);  //  6.4 MB
    const size_t packed_bytes = (size_t)N_EDGES * sizeof(int2);           //  6.4 MB
    const size_t rank_bytes   = (size_t)N_EDGES * sizeof(int);            //  3.2 MB
    const size_t wfrag_bytes  = (size_t)2048 * 8 * sizeof(_Float16);      //  32 KB
    _Float16* aggmh  = (_Float16*)ws;
    _Float16* xh     = (_Float16*)(ws + aggmh_bytes);
    int2*     packed = (int2*)(ws + aggmh_bytes + xh_bytes);
    int*      rank   = (int*)(ws + aggmh_bytes + xh_bytes + packed_bytes);
    _Float16* wfrag  = (_Float16*)(ws + aggmh_bytes + xh_bytes + packed_bytes + rank_bytes);
    int* counts = (int*)(ws + aggmh_bytes + xh_bytes + packed_bytes + rank_bytes + wfrag_bytes);
    int* off    = counts + N_NODES;           // N_NODES+1 entries
    int* bsum   = off + N_NODES + 1;

    hipMemsetAsync(counts, 0, N_NODES * sizeof(int), stream);

    xh_kernel<<<(N_NODES * 16 + 255) / 256, 256, 0, stream>>>(x, xh);
    hist_kernel<<<(N_EDGES + 255) / 256, 256, 0, stream>>>(ei, counts, rank);
    scanA_kernel<<<NB_SCAN, 256, 0, stream>>>(counts, bsum);
    scanC_kernel<<<NB_SCAN, 256, 0, stream>>>(counts, bsum, off);
    scatter_kernel<<<(N_EDGES + 255) / 256, 256, 0, stream>>>(ei, ea, mu, sigma, off, rank, packed);
    wprep_kernel<<<8, 256, 0, stream>>>(g, root, wfrag);
    aggregate_kernel<<<(N_NODES + 3) / 4, 256, 0, stream>>>(xh, packed, off, aggmh);
    mfma_gemm_kernel<<<(N_NODES + 63) / 64, 256, 0, stream>>>(aggmh, wfrag, bias, out);
}

// Round 11
// 107.962 us; speedup vs baseline: 1.2486x; 1.0363x over previous
//
#include <hip/hip_runtime.h>

#define N_NODES 50000
#define N_EDGES 800000
#define NB_SCAN 196   // ceil(N_NODES/256)

typedef _Float16 f16x8 __attribute__((ext_vector_type(8)));
typedef _Float16 f16x4 __attribute__((ext_vector_type(4)));
typedef float    f32x4 __attribute__((ext_vector_type(4)));

__device__ __forceinline__ unsigned f16bits(float f) {
    const _Float16 h = (_Float16)f;
    return (unsigned)*(const unsigned short*)&h;
}
__device__ __forceinline__ float f16val(unsigned u) {
    const unsigned short us = (unsigned short)u;
    return (float)*(const _Float16*)&us;
}

// ---------------- K0: x -> fp16 copy; first 50000 threads also zero counts
__global__ void xh_kernel(const float* __restrict__ x, _Float16* __restrict__ xh,
                          int* __restrict__ counts) {
    const int i = blockIdx.x * 256 + threadIdx.x;   // one float4 per thread
    if (i < N_NODES) counts[i] = 0;                 // replaces 43µs runtime fill
    if (i >= N_NODES * 16) return;
    const float4 v = *(const float4*)&x[(size_t)i * 4];
    f16x4 h;
    h[0] = (_Float16)v.x; h[1] = (_Float16)v.y;
    h[2] = (_Float16)v.z; h[3] = (_Float16)v.w;
    *(f16x4*)&xh[(size_t)i * 4] = h;
}

// ---------------- K1: histogram of destination degrees + rank assignment
__global__ void hist_kernel(const int* __restrict__ ei, int* __restrict__ counts,
                            int* __restrict__ rank) {
    int e = blockIdx.x * 256 + threadIdx.x;
    if (e < N_EDGES) rank[e] = atomicAdd(&counts[ei[N_EDGES + e]], 1);
}

// ---------------- K2a: per-block sums of counts
__global__ void scanA_kernel(const int* __restrict__ counts, int* __restrict__ bsum) {
    __shared__ int s[256];
    int i = blockIdx.x * 256 + threadIdx.x;
    s[threadIdx.x] = (i < N_NODES) ? counts[i] : 0;
    __syncthreads();
    for (int d = 128; d > 0; d >>= 1) {
        if (threadIdx.x < d) s[threadIdx.x] += s[threadIdx.x + d];
        __syncthreads();
    }
    if (threadIdx.x == 0) bsum[blockIdx.x] = s[0];
}

// ---------------- K2c: per-element exclusive offsets (block prefix derived in-kernel)
__global__ void scanC_kernel(const int* __restrict__ counts, const int* __restrict__ bsum,
                             int* __restrict__ off) {
    __shared__ int s[256];
    __shared__ int rs[256];
    const int tid = threadIdx.x;
    rs[tid] = (tid < NB_SCAN && tid < blockIdx.x) ? bsum[tid] : 0;
    __syncthreads();
    for (int d = 128; d > 0; d >>= 1) {
        if (tid < d) rs[tid] += rs[tid + d];
        __syncthreads();
    }
    const int boff = rs[0];
    const int i = blockIdx.x * 256 + tid;
    const int v = (i < N_NODES) ? counts[i] : 0;
    s[tid] = v;
    __syncthreads();
    for (int d = 1; d < 256; d <<= 1) {
        int t = (tid >= d) ? s[tid - d] : 0;
        __syncthreads();
        s[tid] += t;
        __syncthreads();
    }
    const int excl = s[tid] - v + boff;
    if (i < N_NODES) off[i] = excl;
    if (i == 0) off[N_NODES] = N_EDGES;
}

// ---------------- K3: compute f16 gaussian weights, scatter 8B {src:u16,w0,w1,w2}
__global__ void scatter_kernel(const int* __restrict__ ei,
                               const float* __restrict__ pseudo,
                               const float* __restrict__ mu,
                               const float* __restrict__ sigma,
                               const int* __restrict__ off,
                               const int* __restrict__ rank,
                               int2* __restrict__ packed) {
    int e = blockIdx.x * 256 + threadIdx.x;
    if (e >= N_EDGES) return;
    const float mu0 = mu[0], mu1 = mu[1], mu2 = mu[2];
    const float s0 = sigma[0], s1 = sigma[1], s2 = sigma[2];
    const float c0 = -0.5f / (1e-14f + s0 * s0);
    const float c1 = -0.5f / (1e-14f + s1 * s1);
    const float c2 = -0.5f / (1e-14f + s2 * s2);
    const int s  = ei[e];
    const int dd = ei[N_EDGES + e];
    const float u = pseudo[e];
    const float d0 = u - mu0, d1 = u - mu1, d2 = u - mu2;
    const unsigned w0 = f16bits(__expf(c0 * d0 * d0));
    const unsigned w1 = f16bits(__expf(c1 * d1 * d1));
    const unsigned w2 = f16bits(__expf(c2 * d2 * d2));
    const int pos = off[dd] + rank[e];
    packed[pos] = make_int2((int)((unsigned)s | (w0 << 16)), (int)(w1 | (w2 << 16)));
}

// ---------------- K4: wave-per-node gather. Records loaded 64-wide coalesced,
// walked via __shfl broadcast; 4 independent xh-gathers in flight per step.
__global__ void aggregate_kernel(const _Float16* __restrict__ xh,
                                 const int2* __restrict__ packed,
                                 const int* __restrict__ off,
                                 _Float16* __restrict__ aggmh) {
    const int lane = threadIdx.x & 63;
    const int node = blockIdx.x * 4 + (threadIdx.x >> 6);
    if (node >= N_NODES) return;
    const int start = off[node], end = off[node + 1];
    float a0 = 0.f, a1 = 0.f, a2 = 0.f;
    for (int base = start; base < end; base += 64) {
        const int nrec = min(64, end - base);
        int2 rec = make_int2(0, 0);
        if (lane < nrec) rec = packed[base + lane];   // coalesced 64-record load
        int j = 0;
        for (; j + 4 <= nrec; j += 4) {
            const int rx0 = __shfl(rec.x, j + 0), ry0 = __shfl(rec.y, j + 0);
            const int rx1 = __shfl(rec.x, j + 1), ry1 = __shfl(rec.y, j + 1);
            const int rx2 = __shfl(rec.x, j + 2), ry2 = __shfl(rec.y, j + 2);
            const int rx3 = __shfl(rec.x, j + 3), ry3 = __shfl(rec.y, j + 3);
            const float xv0 = (float)xh[(size_t)(rx0 & 0xFFFF) * 64 + lane];
            const float xv1 = (float)xh[(size_t)(rx1 & 0xFFFF) * 64 + lane];
            const float xv2 = (float)xh[(size_t)(rx2 & 0xFFFF) * 64 + lane];
            const float xv3 = (float)xh[(size_t)(rx3 & 0xFFFF) * 64 + lane];
            a0 += f16val((unsigned)rx0 >> 16) * xv0 + f16val((unsigned)rx1 >> 16) * xv1
                + f16val((unsigned)rx2 >> 16) * xv2 + f16val((unsigned)rx3 >> 16) * xv3;
            a1 += f16val(ry0 & 0xFFFF) * xv0 + f16val(ry1 & 0xFFFF) * xv1
                + f16val(ry2 & 0xFFFF) * xv2 + f16val(ry3 & 0xFFFF) * xv3;
            a2 += f16val((unsigned)ry0 >> 16) * xv0 + f16val((unsigned)ry1 >> 16) * xv1
                + f16val((unsigned)ry2 >> 16) * xv2 + f16val((unsigned)ry3 >> 16) * xv3;
        }
        for (; j < nrec; ++j) {
            const int rx = __shfl(rec.x, j), ry = __shfl(rec.y, j);
            const float xv = (float)xh[(size_t)(rx & 0xFFFF) * 64 + lane];
            a0 += f16val((unsigned)rx >> 16) * xv;
            a1 += f16val(ry & 0xFFFF) * xv;
            a2 += f16val((unsigned)ry >> 16) * xv;
        }
    }
    const float inv = 1.0f / fmaxf((float)(end - start), 1.0f);
    _Float16* row = aggmh + (size_t)node * 256;
    row[lane]       = (_Float16)(a0 * inv);
    row[64 + lane]  = (_Float16)(a1 * inv);
    row[128 + lane] = (_Float16)(a2 * inv);
    row[192 + lane] = xh[(size_t)node * 64 + lane];   // for the fused x@root + residual
}

// ---------------- K5a: pre-pack W into MFMA B-fragment layout (fp16)
// W[k][d]: k<192 -> g[k&63][(k>>6)*64+d]; k>=192 -> root[k-192][d]
__global__ void wprep_kernel(const float* __restrict__ g,
                             const float* __restrict__ root,
                             _Float16* __restrict__ wfrag) {
    const int t = blockIdx.x * 256 + threadIdx.x;
    if (t >= 2048) return;
    const int lane = t & 63;
    const int cc   = (t >> 6) & 3;
    const int kc   = t >> 8;
    const int d     = cc * 16 + (lane & 15);
    const int kbase = kc * 32 + (lane >> 4) * 8;
    f16x8 v;
#pragma unroll
    for (int i = 0; i < 8; ++i) {
        const int k = kbase + i;
        const float w = (k < 192) ? g[(k & 63) * 192 + (k >> 6) * 64 + d]
                                  : root[(k - 192) * 64 + d];
        v[i] = (_Float16)w;
    }
    *(f16x8*)&wfrag[(size_t)t * 8] = v;
}

// ---------------- K5b: MFMA GEMM [50000,256]x[256,64] + bias + residual + silu
#define BF(kc, c) (*(const f16x8*)&sWf[((((kc) * 4 + (c)) * 64 + lane) * 8)])
#define MFMA16(a, b, c) __builtin_amdgcn_mfma_f32_16x16x32_f16(a, b, c, 0, 0, 0)
#define COLTILE(c, accv)                                   \
    accv = MFMA16(af0, BF(0, c), accv);                    \
    accv = MFMA16(af1, BF(1, c), accv);                    \
    accv = MFMA16(af2, BF(2, c), accv);                    \
    accv = MFMA16(af3, BF(3, c), accv);                    \
    accv = MFMA16(af4, BF(4, c), accv);                    \
    accv = MFMA16(af5, BF(5, c), accv);                    \
    accv = MFMA16(af6, BF(6, c), accv);                    \
    accv = MFMA16(af7, BF(7, c), accv);
#define EPILOG(c, accv)                                                          \
    {                                                                            \
        const int col = (c) * 16 + (lane & 15);                                  \
        const float bv = bias[col];                                              \
        _Pragma("unroll")                                                        \
        for (int r = 0; r < 4; ++r) {                                            \
            const int rr = orow + r;                                             \
            const float res = (float)aggmh[(size_t)rr * 256 + 192 + col];        \
            const float v = accv[r] + bv + res;                                  \
            out[(size_t)rr * 64 + col] = v / (1.0f + expf(-v));                  \
        }                                                                        \
    }

__global__ __launch_bounds__(256)
void mfma_gemm_kernel(const _Float16* __restrict__ aggmh,
                      const _Float16* __restrict__ wfrag,
                      const float* __restrict__ bias,
                      float* __restrict__ out) {
    __shared__ _Float16 sWf[2048 * 8];   // 32 KB: full W in fragment layout
    const int tid = threadIdx.x;
    for (int i = tid; i < 2048; i += 256)
        *(f16x8*)&sWf[i * 8] = *(const f16x8*)&wfrag[(size_t)i * 8];
    __syncthreads();

    const int lane = tid & 63;
    const int wid  = tid >> 6;
    const int row0 = blockIdx.x * 64 + wid * 16;
    if (row0 >= N_NODES) return;

    const size_t abase = (size_t)(row0 + (lane & 15)) * 256 + (lane >> 4) * 8;
    const f16x8 af0 = *(const f16x8*)&aggmh[abase + 0 * 32];
    const f16x8 af1 = *(const f16x8*)&aggmh[abase + 1 * 32];
    const f16x8 af2 = *(const f16x8*)&aggmh[abase + 2 * 32];
    const f16x8 af3 = *(const f16x8*)&aggmh[abase + 3 * 32];
    const f16x8 af4 = *(const f16x8*)&aggmh[abase + 4 * 32];
    const f16x8 af5 = *(const f16x8*)&aggmh[abase + 5 * 32];
    const f16x8 af6 = *(const f16x8*)&aggmh[abase + 6 * 32];
    const f16x8 af7 = *(const f16x8*)&aggmh[abase + 7 * 32];

    f32x4 acc0 = {0.f, 0.f, 0.f, 0.f};
    f32x4 acc1 = {0.f, 0.f, 0.f, 0.f};
    f32x4 acc2 = {0.f, 0.f, 0.f, 0.f};
    f32x4 acc3 = {0.f, 0.f, 0.f, 0.f};
    COLTILE(0, acc0)
    COLTILE(1, acc1)
    COLTILE(2, acc2)
    COLTILE(3, acc3)

    const int orow = row0 + (lane >> 4) * 4;   // D: col=lane&15, row=(lane>>4)*4+reg
    EPILOG(0, acc0)
    EPILOG(1, acc1)
    EPILOG(2, acc2)
    EPILOG(3, acc3)
}

extern "C" void kernel_launch(void* const* d_in, const int* in_sizes, int n_in,
                              void* d_out, int out_size, void* d_ws, size_t ws_size,
                              hipStream_t stream) {
    const float* x     = (const float*)d_in[0];
    const int*   ei    = (const int*)d_in[1];
    const float* ea    = (const float*)d_in[2];
    const float* g     = (const float*)d_in[3];
    const float* mu    = (const float*)d_in[4];
    const float* sigma = (const float*)d_in[5];
    const float* root  = (const float*)d_in[6];
    const float* bias  = (const float*)d_in[7];
    float* out = (float*)d_out;

    char* ws = (char*)d_ws;
    const size_t aggmh_bytes  = (size_t)N_NODES * 256 * sizeof(_Float16); // 25.6 MB
    const size_t xh_bytes     = (size_t)N_NODES * 64 * sizeof(_Float16);  //  6.4 MB
    const size_t packed_bytes = (size_t)N_EDGES * sizeof(int2);           //  6.4 MB
    const size_t rank_bytes   = (size_t)N_EDGES * sizeof(int);            //  3.2 MB
    const size_t wfrag_bytes  = (size_t)2048 * 8 * sizeof(_Float16);      //  32 KB
    _Float16* aggmh  = (_Float16*)ws;
    _Float16* xh     = (_Float16*)(ws + aggmh_bytes);
    int2*     packed = (int2*)(ws + aggmh_bytes + xh_bytes);
    int*      rank   = (int*)(ws + aggmh_bytes + xh_bytes + packed_bytes);
    _Float16* wfrag  = (_Float16*)(ws + aggmh_bytes + xh_bytes + packed_bytes + rank_bytes);
    int* counts = (int*)(ws + aggmh_bytes + xh_bytes + packed_bytes + rank_bytes + wfrag_bytes);
    int* off    = counts + N_NODES;           // N_NODES+1 entries
    int* bsum   = off + N_NODES + 1;

    xh_kernel<<<(N_NODES * 16 + 255) / 256, 256, 0, stream>>>(x, xh, counts);
    hist_kernel<<<(N_EDGES + 255) / 256, 256, 0, stream>>>(ei, counts, rank);
    scanA_kernel<<<NB_SCAN, 256, 0, stream>>>(counts, bsum);
    scanC_kernel<<<NB_SCAN, 256, 0, stream>>>(counts, bsum, off);
    scatter_kernel<<<(N_EDGES + 255) / 256, 256, 0, stream>>>(ei, ea, mu, sigma, off, rank, packed);
    wprep_kernel<<<8, 256, 0, stream>>>(g, root, wfrag);
    aggregate_kernel<<<(N_NODES + 3) / 4, 256, 0, stream>>>(xh, packed, off, aggmh);
    mfma_gemm_kernel<<<(N_NODES + 63) / 64, 256, 0, stream>>>(aggmh, wfrag, bias, out);
}

// Round 12
// 105.126 us; speedup vs baseline: 1.2823x; 1.0270x over previous
//
#include <hip/hip_runtime.h>

#define N_NODES 50000
#define N_EDGES 800000
#define NB_SCAN 196   // ceil(N_NODES/256)

typedef _Float16 f16x8 __attribute__((ext_vector_type(8)));
typedef _Float16 f16x4 __attribute__((ext_vector_type(4)));
typedef float    f32x4 __attribute__((ext_vector_type(4)));

__device__ __forceinline__ unsigned f16bits(float f) {
    const _Float16 h = (_Float16)f;
    return (unsigned)*(const unsigned short*)&h;
}
__device__ __forceinline__ float f16val(unsigned u) {
    const unsigned short us = (unsigned short)u;
    return (float)*(const _Float16*)&us;
}

// ---------------- K0: x -> fp16 copy; zero counts; blocks 0-7 also pack W frags
// wfrag[t]: lane=t&63, cc=(t>>6)&3, kc=t>>8; d=cc*16+(lane&15), kbase=kc*32+(lane>>4)*8
// W[k][d]: k<192 -> g[k&63][(k>>6)*64+d]; k>=192 -> root[k-192][d]
__global__ void xh_kernel(const float* __restrict__ x, _Float16* __restrict__ xh,
                          int* __restrict__ counts,
                          const float* __restrict__ g, const float* __restrict__ root,
                          _Float16* __restrict__ wfrag) {
    const int i = blockIdx.x * 256 + threadIdx.x;
    if (i < N_NODES) counts[i] = 0;
    if (i < 2048) {   // fused wprep (blocks 0-7)
        const int lane = i & 63;
        const int cc   = (i >> 6) & 3;
        const int kc   = i >> 8;
        const int d     = cc * 16 + (lane & 15);
        const int kbase = kc * 32 + (lane >> 4) * 8;
        f16x8 v;
#pragma unroll
        for (int q = 0; q < 8; ++q) {
            const int k = kbase + q;
            const float w = (k < 192) ? g[(k & 63) * 192 + (k >> 6) * 64 + d]
                                      : root[(k - 192) * 64 + d];
            v[q] = (_Float16)w;
        }
        *(f16x8*)&wfrag[(size_t)i * 8] = v;
    }
    if (i >= N_NODES * 16) return;
    const float4 v = *(const float4*)&x[(size_t)i * 4];
    f16x4 h;
    h[0] = (_Float16)v.x; h[1] = (_Float16)v.y;
    h[2] = (_Float16)v.z; h[3] = (_Float16)v.w;
    *(f16x4*)&xh[(size_t)i * 4] = h;
}

// ---------------- K1: histogram of destination degrees + rank assignment
__global__ void hist_kernel(const int* __restrict__ ei, int* __restrict__ counts,
                            int* __restrict__ rank) {
    int e = blockIdx.x * 256 + threadIdx.x;
    if (e < N_EDGES) rank[e] = atomicAdd(&counts[ei[N_EDGES + e]], 1);
}

// ---------------- K2a: per-block sums of counts
__global__ void scanA_kernel(const int* __restrict__ counts, int* __restrict__ bsum) {
    __shared__ int s[256];
    int i = blockIdx.x * 256 + threadIdx.x;
    s[threadIdx.x] = (i < N_NODES) ? counts[i] : 0;
    __syncthreads();
    for (int d = 128; d > 0; d >>= 1) {
        if (threadIdx.x < d) s[threadIdx.x] += s[threadIdx.x + d];
        __syncthreads();
    }
    if (threadIdx.x == 0) bsum[blockIdx.x] = s[0];
}

// ---------------- K2c: per-element exclusive offsets (block prefix derived in-kernel)
__global__ void scanC_kernel(const int* __restrict__ counts, const int* __restrict__ bsum,
                             int* __restrict__ off) {
    __shared__ int s[256];
    __shared__ int rs[256];
    const int tid = threadIdx.x;
    rs[tid] = (tid < NB_SCAN && tid < blockIdx.x) ? bsum[tid] : 0;
    __syncthreads();
    for (int d = 128; d > 0; d >>= 1) {
        if (tid < d) rs[tid] += rs[tid + d];
        __syncthreads();
    }
    const int boff = rs[0];
    const int i = blockIdx.x * 256 + tid;
    const int v = (i < N_NODES) ? counts[i] : 0;
    s[tid] = v;
    __syncthreads();
    for (int d = 1; d < 256; d <<= 1) {
        int t = (tid >= d) ? s[tid - d] : 0;
        __syncthreads();
        s[tid] += t;
        __syncthreads();
    }
    const int excl = s[tid] - v + boff;
    if (i < N_NODES) off[i] = excl;
    if (i == 0) off[N_NODES] = N_EDGES;
}

// ---------------- K3: scatter 4B {src:u16, u:q16} records to CSR positions
__global__ void scatter_kernel(const int* __restrict__ ei,
                               const float* __restrict__ pseudo,
                               const int* __restrict__ off,
                               const int* __restrict__ rank,
                               unsigned* __restrict__ packed) {
    int e = blockIdx.x * 256 + threadIdx.x;
    if (e >= N_EDGES) return;
    const int s  = ei[e];
    const int dd = ei[N_EDGES + e];
    const unsigned uq = __float2uint_rn(__saturatef(pseudo[e]) * 65535.0f);
    const int pos = off[dd] + rank[e];
    packed[pos] = (unsigned)s | (uq << 16);
}

// ---------------- K4: wave-per-node gather. 4B records loaded 64-wide coalesced;
// each lane computes its record's 3 gaussian weights (f16-packed), then the wave
// walks records via __shfl with 8 independent xh-gathers in flight.
__global__ void aggregate_kernel(const _Float16* __restrict__ xh,
                                 const unsigned* __restrict__ packed,
                                 const int* __restrict__ off,
                                 const float* __restrict__ mu,
                                 const float* __restrict__ sigma,
                                 _Float16* __restrict__ aggmh) {
    const int lane = threadIdx.x & 63;
    const int node = blockIdx.x * 4 + (threadIdx.x >> 6);
    if (node >= N_NODES) return;
    const float mu0 = mu[0], mu1 = mu[1], mu2 = mu[2];
    const float s0 = sigma[0], s1 = sigma[1], s2 = sigma[2];
    const float c0 = -0.5f / (1e-14f + s0 * s0);
    const float c1 = -0.5f / (1e-14f + s1 * s1);
    const float c2 = -0.5f / (1e-14f + s2 * s2);
    const int start = off[node], end = off[node + 1];
    float a0 = 0.f, a1 = 0.f, a2 = 0.f;

#define GATH(q)                                                              \
    const unsigned wa##q = (unsigned)__shfl((int)wa, j + q);                 \
    const unsigned wb##q = (unsigned)__shfl((int)wb, j + q);                 \
    const float xv##q = (float)xh[(size_t)(wb##q & 0xFFFFu) * 64 + lane];
#define ACCU(q)                                                              \
    a0 += f16val(wa##q & 0xFFFFu) * xv##q;                                   \
    a1 += f16val(wa##q >> 16) * xv##q;                                       \
    a2 += f16val(wb##q >> 16) * xv##q;

    for (int base = start; base < end; base += 64) {
        const int nrec = min(64, end - base);
        unsigned rec = 0;
        if (lane < nrec) rec = packed[base + lane];   // coalesced 4B/lane
        // per-lane weight computation for its own record (3 exps/edge total)
        const float u = (float)(rec >> 16) * (1.0f / 65535.0f);
        const float d0 = u - mu0, d1 = u - mu1, d2 = u - mu2;
        const unsigned wa = f16bits(__expf(c0 * d0 * d0))
                          | (f16bits(__expf(c1 * d1 * d1)) << 16);
        const unsigned wb = (rec & 0xFFFFu)
                          | (f16bits(__expf(c2 * d2 * d2)) << 16);
        int j = 0;
        for (; j + 8 <= nrec; j += 8) {
            GATH(0) GATH(1) GATH(2) GATH(3) GATH(4) GATH(5) GATH(6) GATH(7)
            ACCU(0) ACCU(1) ACCU(2) ACCU(3) ACCU(4) ACCU(5) ACCU(6) ACCU(7)
        }
        for (; j + 4 <= nrec; j += 4) {
            GATH(0) GATH(1) GATH(2) GATH(3)
            ACCU(0) ACCU(1) ACCU(2) ACCU(3)
        }
        for (; j < nrec; ++j) {
            GATH(0)
            ACCU(0)
        }
    }
#undef GATH
#undef ACCU
    const float inv = 1.0f / fmaxf((float)(end - start), 1.0f);
    _Float16* row = aggmh + (size_t)node * 256;
    row[lane]       = (_Float16)(a0 * inv);
    row[64 + lane]  = (_Float16)(a1 * inv);
    row[128 + lane] = (_Float16)(a2 * inv);
    row[192 + lane] = xh[(size_t)node * 64 + lane];   // for the fused x@root + residual
}

// ---------------- K5: MFMA GEMM [50000,256]x[256,64] + bias + residual + silu
#define BF(kc, c) (*(const f16x8*)&sWf[((((kc) * 4 + (c)) * 64 + lane) * 8)])
#define MFMA16(a, b, c) __builtin_amdgcn_mfma_f32_16x16x32_f16(a, b, c, 0, 0, 0)
#define COLTILE(c, accv)                                   \
    accv = MFMA16(af0, BF(0, c), accv);                    \
    accv = MFMA16(af1, BF(1, c), accv);                    \
    accv = MFMA16(af2, BF(2, c), accv);                    \
    accv = MFMA16(af3, BF(3, c), accv);                    \
    accv = MFMA16(af4, BF(4, c), accv);                    \
    accv = MFMA16(af5, BF(5, c), accv);                    \
    accv = MFMA16(af6, BF(6, c), accv);                    \
    accv = MFMA16(af7, BF(7, c), accv);
#define EPILOG(c, accv)                                                          \
    {                                                                            \
        const int col = (c) * 16 + (lane & 15);                                  \
        const float bv = bias[col];                                              \
        _Pragma("unroll")                                                        \
        for (int r = 0; r < 4; ++r) {                                            \
            const int rr = orow + r;                                             \
            const float res = (float)aggmh[(size_t)rr * 256 + 192 + col];        \
            const float v = accv[r] + bv + res;                                  \
            out[(size_t)rr * 64 + col] = v / (1.0f + expf(-v));                  \
        }                                                                        \
    }

__global__ __launch_bounds__(256)
void mfma_gemm_kernel(const _Float16* __restrict__ aggmh,
                      const _Float16* __restrict__ wfrag,
                      const float* __restrict__ bias,
                      float* __restrict__ out) {
    __shared__ _Float16 sWf[2048 * 8];   // 32 KB: full W in fragment layout
    const int tid = threadIdx.x;
    for (int i = tid; i < 2048; i += 256)
        *(f16x8*)&sWf[i * 8] = *(const f16x8*)&wfrag[(size_t)i * 8];
    __syncthreads();

    const int lane = tid & 63;
    const int wid  = tid >> 6;
    const int row0 = blockIdx.x * 64 + wid * 16;
    if (row0 >= N_NODES) return;

    const size_t abase = (size_t)(row0 + (lane & 15)) * 256 + (lane >> 4) * 8;
    const f16x8 af0 = *(const f16x8*)&aggmh[abase + 0 * 32];
    const f16x8 af1 = *(const f16x8*)&aggmh[abase + 1 * 32];
    const f16x8 af2 = *(const f16x8*)&aggmh[abase + 2 * 32];
    const f16x8 af3 = *(const f16x8*)&aggmh[abase + 3 * 32];
    const f16x8 af4 = *(const f16x8*)&aggmh[abase + 4 * 32];
    const f16x8 af5 = *(const f16x8*)&aggmh[abase + 5 * 32];
    const f16x8 af6 = *(const f16x8*)&aggmh[abase + 6 * 32];
    const f16x8 af7 = *(const f16x8*)&aggmh[abase + 7 * 32];

    f32x4 acc0 = {0.f, 0.f, 0.f, 0.f};
    f32x4 acc1 = {0.f, 0.f, 0.f, 0.f};
    f32x4 acc2 = {0.f, 0.f, 0.f, 0.f};
    f32x4 acc3 = {0.f, 0.f, 0.f, 0.f};
    COLTILE(0, acc0)
    COLTILE(1, acc1)
    COLTILE(2, acc2)
    COLTILE(3, acc3)

    const int orow = row0 + (lane >> 4) * 4;   // D: col=lane&15, row=(lane>>4)*4+reg
    EPILOG(0, acc0)
    EPILOG(1, acc1)
    EPILOG(2, acc2)
    EPILOG(3, acc3)
}

extern "C" void kernel_launch(void* const* d_in, const int* in_sizes, int n_in,
                              void* d_out, int out_size, void* d_ws, size_t ws_size,
                              hipStream_t stream) {
    const float* x     = (const float*)d_in[0];
    const int*   ei    = (const int*)d_in[1];
    const float* ea    = (const float*)d_in[2];
    const float* g     = (const float*)d_in[3];
    const float* mu    = (const float*)d_in[4];
    const float* sigma = (const float*)d_in[5];
    const float* root  = (const float*)d_in[6];
    const float* bias  = (const float*)d_in[7];
    float* out = (float*)d_out;

    char* ws = (char*)d_ws;
    const size_t aggmh_bytes  = (size_t)N_NODES * 256 * sizeof(_Float16); // 25.6 MB
    const size_t xh_bytes     = (size_t)N_NODES * 64 * sizeof(_Float16);  //  6.4 MB
    const size_t packed_bytes = (size_t)N_EDGES * sizeof(unsigned);       //  3.2 MB
    const size_t rank_bytes   = (size_t)N_EDGES * sizeof(int);            //  3.2 MB
    const size_t wfrag_bytes  = (size_t)2048 * 8 * sizeof(_Float16);      //  32 KB
    _Float16* aggmh  = (_Float16*)ws;
    _Float16* xh     = (_Float16*)(ws + aggmh_bytes);
    unsigned* packed = (unsigned*)(ws + aggmh_bytes + xh_bytes);
    int*      rank   = (int*)(ws + aggmh_bytes + xh_bytes + packed_bytes);
    _Float16* wfrag  = (_Float16*)(ws + aggmh_bytes + xh_bytes + packed_bytes + rank_bytes);
    int* counts = (int*)(ws + aggmh_bytes + xh_bytes + packed_bytes + rank_bytes + wfrag_bytes);
    int* off    = counts + N_NODES;           // N_NODES+1 entries
    int* bsum   = off + N_NODES + 1;

    xh_kernel<<<(N_NODES * 16 + 255) / 256, 256, 0, stream>>>(x, xh, counts, g, root, wfrag);
    hist_kernel<<<(N_EDGES + 255) / 256, 256, 0, stream>>>(ei, counts, rank);
    scanA_kernel<<<NB_SCAN, 256, 0, stream>>>(counts, bsum);
    scanC_kernel<<<NB_SCAN, 256, 0, stream>>>(counts, bsum, off);
    scatter_kernel<<<(N_EDGES + 255) / 256, 256, 0, stream>>>(ei, ea, off, rank, packed);
    aggregate_kernel<<<(N_NODES + 3) / 4, 256, 0, stream>>>(xh, packed, off, mu, sigma, aggmh);
    mfma_gemm_kernel<<<(N_NODES + 63) / 64, 256, 0, stream>>>(aggmh, wfrag, bias, out);
}